// Round 14
// baseline (183.781 us; speedup 1.0000x reference)
//
#include <hip/hip_runtime.h>
#include <hip/hip_bf16.h>

typedef __attribute__((ext_vector_type(8))) short short8_t;
typedef __attribute__((ext_vector_type(4))) float f32x4_t;

#define NOUT 8192
#define NIN 32768
#define MTOT 262144.0f   // B * NOUT
#define ST_STRIPES 64
#define SLICE 2097152    // 8192 n * 256 elems per bh-slice of out1

#define MF(a,b,c) __builtin_amdgcn_mfma_f32_16x16x32_bf16((a),(b),(c),0,0,0)

static __device__ __forceinline__ float bf2f(ushort u) {
    union { float f; unsigned int i; } x; x.i = ((unsigned int)u) << 16; return x.f;
}
static __device__ __forceinline__ ushort f2bfx(float f) {
    union { __hip_bfloat16 h; ushort u; } v;
    v.h = __float2bfloat16(f);   // hw v_cvt RNE on gfx950
    return v.u;
}
static __device__ __forceinline__ short8_t i4s8(int4 v) {
    union { int4 i; short8_t s; } u; u.i = v; return u.s;
}

// BN1+ReLU on 8 packed bf16 with register coefficients, returns MFMA-ready frag
static __device__ __forceinline__ short8_t bn8(int4 v, const float* a8, const float* c8) {
    ushort* pv = (ushort*)&v;
    #pragma unroll
    for (int e = 0; e < 8; ++e)
        pv[e] = f2bfx(fmaxf(a8[e] * bf2f(pv[e]) + c8[e], 0.f));
    return i4s8(v);
}

// ---- x [32][32][32768] f32  ->  xt [32768][1024] bf16 (row = b*32+i) ----
__global__ __launch_bounds__(256) void transpose_x_kernel(
    const float* __restrict__ x, ushort* __restrict__ xt)
{
    __shared__ ushort T[64][66];
    const int tid = threadIdx.x;
    const int n0 = blockIdx.x * 64, c0 = blockIdx.y * 64;
    const int lane64 = tid & 63, rb = (tid >> 6) * 16;
    #pragma unroll
    for (int r = 0; r < 16; ++r) {
        int c_l = rb + r;
        T[c_l][lane64] = f2bfx(x[(size_t)(c0 + c_l) * NIN + n0 + lane64]);
    }
    __syncthreads();
    #pragma unroll
    for (int r = 0; r < 16; ++r) {
        int n_l = rb + r;
        xt[(size_t)(n0 + n_l) * 1024 + c0 + lane64] = T[lane64][n_l];
    }
}

// ---- weight prep into LDS-segment layouts (+ zero stats stripes) ----
__global__ __launch_bounds__(256) void prep_w_kernel(
    const float* __restrict__ W1, const float* __restrict__ W2,
    const float* __restrict__ We,
    ushort* __restrict__ w1p, ushort* __restrict__ w2p, ushort* __restrict__ wep,
    float* __restrict__ stz)
{
    int t = blockIdx.x * 256 + threadIdx.x;
    const int N1 = 18432, N2 = 36864, N3 = 2048;
    if (t < 3 * ST_STRIPES * 128) stz[t] = 0.f;
    if (t < N1) {
        int e = t & 7, o = (t >> 3) & 63, seg = t >> 9;   // seg = k*4+fcg
        int fcg = seg & 3, k = seg >> 2;
        int i = fcg * 8 + e;
        w1p[t] = f2bfx(W1[o * 288 + i * 9 + k]);
    } else if (t < N1 + N2) {
        int t2 = t - N1;
        int e = t2 & 7, o = (t2 >> 3) & 63, seg = t2 >> 9; // seg = k*8+kk*4+fcg
        int fcg = seg & 3, kk = (seg >> 2) & 1, k = seg >> 3;
        int ci = kk * 32 + fcg * 8 + e;
        w2p[t2] = f2bfx(W2[o * 576 + ci * 9 + k]);
    } else if (t < N1 + N2 + N3) {
        int t3 = t - N1 - N2;
        wep[t3] = f2bfx(We[t3]);
    }
}

// ---- conv1 + ident fused: 8 waves/block, wave owns one n.
//      W1 in LDS; conv A-gather depth-4 pipeline; pool gathers ride the tail;
//      ident MFMA reuses acc.  out1 written in XCD-SLICED layout
//      [bh=b>>2][n][b&3][ch].  idt stays [n][b*64+o]. ----
__global__ __launch_bounds__(512, 2) void conv1i_kernel(
    const ushort* __restrict__ xt, const int* __restrict__ idx1,
    const int* __restrict__ pool_idx, const ushort* __restrict__ w1p,
    const ushort* __restrict__ wep,
    ushort* __restrict__ out1, ushort* __restrict__ identt,
    float* __restrict__ st1g, float* __restrict__ st3g)
{
    __shared__ __align__(16) ushort Wl[18432];   // 36864 B
    __shared__ float Ls1[128], Ls3[128];
    const int tid = threadIdx.x;
    const int lane = tid & 63, wv = tid >> 6;
    const int n = __builtin_amdgcn_readfirstlane(blockIdx.x * 8 + wv);
    const int l15 = lane & 15, fcg = lane >> 4, fc = fcg * 8;

    for (int i = tid; i < 2304; i += 512)
        ((int4*)Wl)[i] = ((const int4*)w1p)[i];
    if (tid < 128) { Ls1[tid] = 0.f; Ls3[tid] = 0.f; }

    int rows[9], prow[4];
    {
        const int* idxn = idx1 + n * 9;
        #pragma unroll
        for (int t = 0; t < 9; ++t) rows[t] = idxn[t];
        const int* pn = pool_idx + n * 4;
        #pragma unroll
        for (int t = 0; t < 4; ++t) prow[t] = pn[t];
    }
    __syncthreads();

    f32x4_t acc[2][4];
    #pragma unroll
    for (int m = 0; m < 2; ++m)
        #pragma unroll
        for (int nt = 0; nt < 4; ++nt) acc[m][nt] = (f32x4_t){0.f, 0.f, 0.f, 0.f};

    int4 A0[2], A1[2], A2[2], A3[2];

#define C1_PRE(K, A) { \
    const ushort* rp = xt + (size_t)rows[K] * 1024 + l15 * 32 + fc; \
    A[0] = *(const int4*)rp; \
    A[1] = *(const int4*)(rp + 512); }

#define C1_PPRE(KP, A) { \
    const ushort* rp = xt + (size_t)prow[KP] * 1024 + l15 * 32 + fc; \
    A[0] = *(const int4*)rp; \
    A[1] = *(const int4*)(rp + 512); }

#define C1_BODY(K, A) { \
    const ushort* wp = Wl + ((K) * 4 + fcg) * 512; \
    short8_t b0 = *(const short8_t*)(wp + l15 * 8); \
    short8_t b1 = *(const short8_t*)(wp + (16 + l15) * 8); \
    short8_t b2 = *(const short8_t*)(wp + (32 + l15) * 8); \
    short8_t b3 = *(const short8_t*)(wp + (48 + l15) * 8); \
    short8_t af0 = i4s8(A[0]), af1 = i4s8(A[1]); \
    acc[0][0] = MF(af0, b0, acc[0][0]); acc[1][0] = MF(af1, b0, acc[1][0]); \
    acc[0][1] = MF(af0, b1, acc[0][1]); acc[1][1] = MF(af1, b1, acc[1][1]); \
    acc[0][2] = MF(af0, b2, acc[0][2]); acc[1][2] = MF(af1, b2, acc[1][2]); \
    acc[0][3] = MF(af0, b3, acc[0][3]); acc[1][3] = MF(af1, b3, acc[1][3]); }

    C1_PRE(0, A0); C1_PRE(1, A1); C1_PRE(2, A2); C1_PRE(3, A3);
    C1_BODY(0, A0); C1_PRE(4, A0);
    C1_BODY(1, A1); C1_PRE(5, A1);
    C1_BODY(2, A2); C1_PRE(6, A2);
    C1_BODY(3, A3); C1_PRE(7, A3);
    C1_BODY(4, A0); C1_PRE(8, A0);
    C1_BODY(5, A1); C1_PPRE(0, A1);
    C1_BODY(6, A2); C1_PPRE(1, A2);
    C1_BODY(7, A3); C1_PPRE(2, A3);
    C1_BODY(8, A0);
#undef C1_PRE
#undef C1_BODY

    // conv epilogue: store raw out1 in SLICED layout + stats1
    #pragma unroll
    for (int m = 0; m < 2; ++m)
        #pragma unroll
        for (int nt = 0; nt < 4; ++nt)
            #pragma unroll
            for (int j = 0; j < 4; ++j) {
                int b = m * 16 + (lane >> 4) * 4 + j;
                int o = nt * 16 + l15;
                out1[(size_t)(b >> 2) * SLICE + (size_t)n * 256 + (b & 3) * 64 + o]
                    = f2bfx(acc[m][nt][j]);
            }
    #pragma unroll
    for (int nt = 0; nt < 4; ++nt) {
        float s = 0.f, q = 0.f;
        #pragma unroll
        for (int m = 0; m < 2; ++m)
            #pragma unroll
            for (int j = 0; j < 4; ++j) { float v = acc[m][nt][j]; s += v; q += v * v; }
        s += __shfl_xor(s, 16); s += __shfl_xor(s, 32);
        q += __shfl_xor(q, 16); q += __shfl_xor(q, 32);
        if (lane < 16) {
            atomicAdd(&Ls1[nt * 16 + lane], s);
            atomicAdd(&Ls1[64 + nt * 16 + lane], q);
        }
    }

    // pool: last row + sum (A1..A3 hold pool rows 0..2)
    int4 P3[2];
    C1_PPRE(3, P3);
#undef C1_PPRE
    float s0[8], s1[8];
    #pragma unroll
    for (int e = 0; e < 8; ++e) { s0[e] = 0.f; s1[e] = 0.f; }
    {
        const ushort* p;
        p = (const ushort*)&A1[0];
        #pragma unroll
        for (int e = 0; e < 8; ++e) s0[e] += bf2f(p[e]);
        p = (const ushort*)&A1[1];
        #pragma unroll
        for (int e = 0; e < 8; ++e) s1[e] += bf2f(p[e]);
        p = (const ushort*)&A2[0];
        #pragma unroll
        for (int e = 0; e < 8; ++e) s0[e] += bf2f(p[e]);
        p = (const ushort*)&A2[1];
        #pragma unroll
        for (int e = 0; e < 8; ++e) s1[e] += bf2f(p[e]);
        p = (const ushort*)&A3[0];
        #pragma unroll
        for (int e = 0; e < 8; ++e) s0[e] += bf2f(p[e]);
        p = (const ushort*)&A3[1];
        #pragma unroll
        for (int e = 0; e < 8; ++e) s1[e] += bf2f(p[e]);
        p = (const ushort*)&P3[0];
        #pragma unroll
        for (int e = 0; e < 8; ++e) s0[e] += bf2f(p[e]);
        p = (const ushort*)&P3[1];
        #pragma unroll
        for (int e = 0; e < 8; ++e) s1[e] += bf2f(p[e]);
    }
    short8_t paf0, paf1;
    {
        int4 v0, v1; ushort* p0 = (ushort*)&v0; ushort* p1 = (ushort*)&v1;
        #pragma unroll
        for (int e = 0; e < 8; ++e) {
            p0[e] = f2bfx(s0[e] * 0.25f);
            p1[e] = f2bfx(s1[e] * 0.25f);
        }
        paf0 = i4s8(v0); paf1 = i4s8(v1);
    }
    short8_t bfr[4];
    {
        const ushort* wpf = wep + l15 * 32 + fc;
        #pragma unroll
        for (int nt = 0; nt < 4; ++nt)
            bfr[nt] = *(const short8_t*)(wpf + nt * 512);
    }
    #pragma unroll
    for (int nt = 0; nt < 4; ++nt) {
        acc[0][nt] = (f32x4_t){0.f, 0.f, 0.f, 0.f};
        acc[1][nt] = (f32x4_t){0.f, 0.f, 0.f, 0.f};
        acc[0][nt] = MF(paf0, bfr[nt], acc[0][nt]);
        acc[1][nt] = MF(paf1, bfr[nt], acc[1][nt]);
    }
    const size_t outbase = (size_t)n * 2048;
    #pragma unroll
    for (int m = 0; m < 2; ++m)
        #pragma unroll
        for (int nt = 0; nt < 4; ++nt)
            #pragma unroll
            for (int j = 0; j < 4; ++j) {
                int b = m * 16 + (lane >> 4) * 4 + j;
                int o = nt * 16 + l15;
                identt[outbase + b * 64 + o] = f2bfx(acc[m][nt][j]);
            }
    #pragma unroll
    for (int nt = 0; nt < 4; ++nt) {
        float s = 0.f, q = 0.f;
        #pragma unroll
        for (int m = 0; m < 2; ++m)
            #pragma unroll
            for (int j = 0; j < 4; ++j) { float v = acc[m][nt][j]; s += v; q += v * v; }
        s += __shfl_xor(s, 16); s += __shfl_xor(s, 32);
        q += __shfl_xor(q, 16); q += __shfl_xor(q, 32);
        if (lane < 16) {
            atomicAdd(&Ls3[nt * 16 + lane], s);
            atomicAdd(&Ls3[64 + nt * 16 + lane], q);
        }
    }
    __syncthreads();
    if (tid < 128) {
        atomicAdd(&st1g[(blockIdx.x & (ST_STRIPES - 1)) * 128 + tid], Ls1[tid]);
        atomicAdd(&st3g[(blockIdx.x & (ST_STRIPES - 1)) * 128 + tid], Ls3[tid]);
    }
}

// ---- conv2, XCD-sliced: block handles bh = blockIdx.x & 7; its gathers touch
//      ONLY out1 slice bh (4 MB = one XCD's L2). Wave = 8 n x 4 b rows.
//      W2 in LDS; A gathered direct-to-fragment with per-lane row indices;
//      BN1+ReLU fused in regs; depth-3 pipeline. ----
__global__ __launch_bounds__(512, 2) void conv2_kernel(
    const ushort* __restrict__ out1raw, const int* __restrict__ idx2,
    const ushort* __restrict__ w2p, const float* __restrict__ ac1,
    ushort* __restrict__ out2, float* __restrict__ st)
{
    __shared__ __align__(16) ushort Wl[36864];   // 73728 B
    __shared__ float Ls[128];
    const int tid = threadIdx.x;
    const int lane = tid & 63, wv = tid >> 6;
    const int bh = __builtin_amdgcn_readfirstlane(blockIdx.x & 7);
    const int n0 = __builtin_amdgcn_readfirstlane((blockIdx.x >> 3) * 64 + wv * 8);
    const int l15 = lane & 15, fcg = lane >> 4, fc = fcg * 8;
    const int bl = l15 & 3;                  // b_local for A-rows
    const ushort* out1s = out1raw + (size_t)bh * SLICE;

    for (int i = tid; i < 4608; i += 512)
        ((int4*)Wl)[i] = ((const int4*)w2p)[i];
    if (tid < 128) Ls[tid] = 0.f;

    // per-lane row indices: m=0 rows use n0 + (l15>>2), m=1 rows n0+4+(l15>>2)
    int r0[9], r1[9];
    {
        const int* ip0 = idx2 + (n0 + (l15 >> 2)) * 9;
        const int* ip1 = ip0 + 36;   // (n0+4+(l15>>2))*9
        #pragma unroll
        for (int t = 0; t < 9; ++t) { r0[t] = ip0[t]; r1[t] = ip1[t]; }
    }
    float a0r[8], c0r[8], a1r[8], c1r[8];
    #pragma unroll
    for (int e = 0; e < 8; ++e) {
        a0r[e] = ac1[fc + e];       c0r[e] = ac1[64 + fc + e];
        a1r[e] = ac1[32 + fc + e];  c1r[e] = ac1[96 + fc + e];
    }
    __syncthreads();

    f32x4_t acc[2][4];
    #pragma unroll
    for (int m = 0; m < 2; ++m)
        #pragma unroll
        for (int nt = 0; nt < 4; ++nt) acc[m][nt] = (f32x4_t){0.f, 0.f, 0.f, 0.f};

    int4 A0[4], A1[4], A2[4];

#define C2_PRE(K, A) { \
    const ushort* rp0 = out1s + (size_t)r0[K] * 256 + bl * 64 + fc; \
    const ushort* rp1 = out1s + (size_t)r1[K] * 256 + bl * 64 + fc; \
    A[0] = *(const int4*)rp0; \
    A[1] = *(const int4*)(rp0 + 32); \
    A[2] = *(const int4*)rp1; \
    A[3] = *(const int4*)(rp1 + 32); }

#define C2_BODY(K, A) { \
    const ushort* wp0 = Wl + ((K) * 8 + fcg) * 512; \
    const ushort* wp1 = wp0 + 2048; \
    short8_t b00 = *(const short8_t*)(wp0 + l15 * 8); \
    short8_t b10 = *(const short8_t*)(wp0 + (16 + l15) * 8); \
    short8_t b20 = *(const short8_t*)(wp0 + (32 + l15) * 8); \
    short8_t b30 = *(const short8_t*)(wp0 + (48 + l15) * 8); \
    short8_t b01 = *(const short8_t*)(wp1 + l15 * 8); \
    short8_t b11 = *(const short8_t*)(wp1 + (16 + l15) * 8); \
    short8_t b21 = *(const short8_t*)(wp1 + (32 + l15) * 8); \
    short8_t b31 = *(const short8_t*)(wp1 + (48 + l15) * 8); \
    short8_t af00 = bn8(A[0], a0r, c0r); \
    short8_t af01 = bn8(A[1], a1r, c1r); \
    short8_t af10 = bn8(A[2], a0r, c0r); \
    short8_t af11 = bn8(A[3], a1r, c1r); \
    acc[0][0] = MF(af00, b00, acc[0][0]); acc[0][0] = MF(af01, b01, acc[0][0]); \
    acc[0][1] = MF(af00, b10, acc[0][1]); acc[0][1] = MF(af01, b11, acc[0][1]); \
    acc[0][2] = MF(af00, b20, acc[0][2]); acc[0][2] = MF(af01, b21, acc[0][2]); \
    acc[0][3] = MF(af00, b30, acc[0][3]); acc[0][3] = MF(af01, b31, acc[0][3]); \
    acc[1][0] = MF(af10, b00, acc[1][0]); acc[1][0] = MF(af11, b01, acc[1][0]); \
    acc[1][1] = MF(af10, b10, acc[1][1]); acc[1][1] = MF(af11, b11, acc[1][1]); \
    acc[1][2] = MF(af10, b20, acc[1][2]); acc[1][2] = MF(af11, b21, acc[1][2]); \
    acc[1][3] = MF(af10, b30, acc[1][3]); acc[1][3] = MF(af11, b31, acc[1][3]); }

    C2_PRE(0, A0); C2_PRE(1, A1); C2_PRE(2, A2);
    C2_BODY(0, A0); C2_PRE(3, A0);
    C2_BODY(1, A1); C2_PRE(4, A1);
    C2_BODY(2, A2); C2_PRE(5, A2);
    C2_BODY(3, A0); C2_PRE(6, A0);
    C2_BODY(4, A1); C2_PRE(7, A1);
    C2_BODY(5, A2); C2_PRE(8, A2);
    C2_BODY(6, A0);
    C2_BODY(7, A1);
    C2_BODY(8, A2);
#undef C2_PRE
#undef C2_BODY

    // out2 stays [n][b*64+o]; wave's rows are (n0+m*4+(lane>>4), b=bh*4+j)
    #pragma unroll
    for (int m = 0; m < 2; ++m)
        #pragma unroll
        for (int nt = 0; nt < 4; ++nt)
            #pragma unroll
            for (int j = 0; j < 4; ++j) {
                int nn = n0 + m * 4 + (lane >> 4);
                int bcol = bh * 4 + j;
                int o = nt * 16 + l15;
                out2[(size_t)nn * 2048 + bcol * 64 + o] = f2bfx(acc[m][nt][j]);
            }
    #pragma unroll
    for (int nt = 0; nt < 4; ++nt) {
        float s = 0.f, q = 0.f;
        #pragma unroll
        for (int m = 0; m < 2; ++m)
            #pragma unroll
            for (int j = 0; j < 4; ++j) { float v = acc[m][nt][j]; s += v; q += v * v; }
        s += __shfl_xor(s, 16); s += __shfl_xor(s, 32);
        q += __shfl_xor(q, 16); q += __shfl_xor(q, 32);
        if (lane < 16) {
            atomicAdd(&Ls[nt * 16 + lane], s);
            atomicAdd(&Ls[64 + nt * 16 + lane], q);
        }
    }
    __syncthreads();
    if (tid < 128) atomicAdd(&st[(blockIdx.x & (ST_STRIPES - 1)) * 128 + tid], Ls[tid]);
}

// ---- finalize BN affine from striped partials ----
__global__ void finalize_kernel(const float* __restrict__ st, const float* __restrict__ g,
                                const float* __restrict__ bet, float* __restrict__ ac)
{
    int o = threadIdx.x;
    if (o >= 64) return;
    float s = 0.f, q = 0.f;
    for (int i = 0; i < ST_STRIPES; ++i) { s += st[i * 128 + o]; q += st[i * 128 + 64 + o]; }
    float mean = s * (1.0f / MTOT);
    float var  = q * (1.0f / MTOT) - mean * mean;
    float a = g[o] * rsqrtf(var + 1e-5f);
    ac[o] = a;
    ac[64 + o] = bet[o] - a * mean;
}

__global__ void finalize_dual_kernel(
    const float* __restrict__ stA, const float* __restrict__ gA, const float* __restrict__ bA,
    const float* __restrict__ stB, const float* __restrict__ gB, const float* __restrict__ bB,
    float* __restrict__ acA, float* __restrict__ acB)
{
    int o = threadIdx.x;
    if (o >= 64) return;
    const float* st = blockIdx.x ? stB : stA;
    const float* g  = blockIdx.x ? gB  : gA;
    const float* bt = blockIdx.x ? bB  : bA;
    float* ac       = blockIdx.x ? acB : acA;
    float s = 0.f, q = 0.f;
    for (int i = 0; i < ST_STRIPES; ++i) { s += st[i * 128 + o]; q += st[i * 128 + 64 + o]; }
    float mean = s * (1.0f / MTOT);
    float var  = q * (1.0f / MTOT) - mean * mean;
    float a = g[o] * rsqrtf(var + 1e-5f);
    ac[o] = a;
    ac[64 + o] = bt[o] - a * mean;
}

// ---- final: d_out[bo][n] = relu(a2*out2 + c2 + a3*identt + c3), with transpose ----
__global__ __launch_bounds__(256) void final_combine_kernel(
    const ushort* __restrict__ out2, const ushort* __restrict__ idt,
    const float* __restrict__ ac2, const float* __restrict__ ac3,
    float* __restrict__ dout)
{
    __shared__ float tile[64][65];
    const int tid = threadIdx.x;
    const int n0 = blockIdx.x * 64, bo0 = blockIdx.y * 64;
    const int lane64 = tid & 63, rb = (tid >> 6) * 16;
    const int o = lane64;  // bo0 is a multiple of 64
    const float a2 = ac2[o], c2 = ac2[64 + o], a3 = ac3[o], c3 = ac3[64 + o];
    #pragma unroll
    for (int r = 0; r < 16; ++r) {
        int n_l = rb + r;
        size_t p = (size_t)(n0 + n_l) * 2048 + bo0 + lane64;
        float v = a2 * bf2f(out2[p]) + c2 + a3 * bf2f(idt[p]) + c3;
        tile[n_l][lane64] = fmaxf(v, 0.f);
    }
    __syncthreads();
    #pragma unroll
    for (int r = 0; r < 16; ++r) {
        int bo_l = rb + r;
        dout[(size_t)(bo0 + bo_l) * NOUT + n0 + lane64] = tile[lane64][bo_l];
    }
}

extern "C" void kernel_launch(void* const* d_in, const int* in_sizes, int n_in,
                              void* d_out, int out_size, void* d_ws, size_t ws_size,
                              hipStream_t stream)
{
    const float* x     = (const float*)d_in[0];
    const float* W1    = (const float*)d_in[1];
    const float* W2    = (const float*)d_in[3];
    const float* We    = (const float*)d_in[5];
    const float* g1    = (const float*)d_in[7];
    const float* beta1 = (const float*)d_in[8];
    const float* g2    = (const float*)d_in[9];
    const float* beta2 = (const float*)d_in[10];
    const float* g3    = (const float*)d_in[11];
    const float* beta3 = (const float*)d_in[12];
    const int* idx1    = (const int*)d_in[13];
    const int* idx2    = (const int*)d_in[14];
    const int* pool_idx= (const int*)d_in[15];
    float* dout = (float*)d_out;

    char* ws = (char*)d_ws;
    const size_t off_xt   = 0;                    // 67108864
    const size_t off_out1 = 67108864;             // 33554432
    const size_t off_out2 = 100663296;             // 33554432
    const size_t off_id   = 134217728;             // 33554432
    const size_t off_w1p  = 167772160;             // 36864
    const size_t off_w2p  = 167809024;             // 73728
    const size_t off_wep  = 167882752;             // 4096
    const size_t off_st   = 167886848;             // 3 * 64*128*4 = 98304
    const size_t off_ac   = 167985152;             // 1536
    const size_t need     = 167986688;
    if (ws_size < need) return;  // insufficient workspace — fail visibly

    ushort* xt   = (ushort*)(ws + off_xt);
    ushort* out1 = (ushort*)(ws + off_out1);
    ushort* out2 = (ushort*)(ws + off_out2);
    ushort* idt  = (ushort*)(ws + off_id);
    ushort* w1p  = (ushort*)(ws + off_w1p);
    ushort* w2p  = (ushort*)(ws + off_w2p);
    ushort* wep  = (ushort*)(ws + off_wep);
    float*  st1  = (float*)(ws + off_st);
    float*  st2  = st1 + 64 * 128;
    float*  st3  = st1 + 2 * 64 * 128;
    float*  ac1  = (float*)(ws + off_ac);
    float*  ac2  = ac1 + 128;
    float*  ac3  = ac1 + 256;

    prep_w_kernel<<<224, 256, 0, stream>>>(W1, W2, We, w1p, w2p, wep, st1);
    transpose_x_kernel<<<dim3(512, 16), 256, 0, stream>>>(x, xt);
    conv1i_kernel<<<1024, 512, 0, stream>>>(xt, idx1, pool_idx, w1p, wep, out1, idt, st1, st3);
    finalize_dual_kernel<<<2, 64, 0, stream>>>(st1, g1, beta1, st3, g3, beta3, ac1, ac3);
    conv2_kernel<<<1024, 512, 0, stream>>>(out1, idx2, w2p, ac1, out2, st2);
    finalize_kernel<<<1, 64, 0, stream>>>(st2, g2, beta2, ac2);
    final_combine_kernel<<<dim3(128, 32), 256, 0, stream>>>(out2, idt, ac2, ac3, dout);
}

// Round 15
// 168.067 us; speedup vs baseline: 1.0935x; 1.0935x over previous
//
#include <hip/hip_runtime.h>
#include <hip/hip_bf16.h>

typedef __attribute__((ext_vector_type(8))) short short8_t;
typedef __attribute__((ext_vector_type(4))) float f32x4_t;

#define NOUT 8192
#define NIN 32768
#define MTOT 262144.0f   // B * NOUT
#define ST_STRIPES 64

#define MF(a,b,c) __builtin_amdgcn_mfma_f32_16x16x32_bf16((a),(b),(c),0,0,0)

static __device__ __forceinline__ float bf2f(ushort u) {
    union { float f; unsigned int i; } x; x.i = ((unsigned int)u) << 16; return x.f;
}
static __device__ __forceinline__ ushort f2bfx(float f) {
    union { __hip_bfloat16 h; ushort u; } v;
    v.h = __float2bfloat16(f);   // hw v_cvt RNE on gfx950
    return v.u;
}
static __device__ __forceinline__ short8_t i4s8(int4 v) {
    union { int4 i; short8_t s; } u; u.i = v; return u.s;
}

// BN1+ReLU on 8 packed bf16 with register coefficients, returns MFMA-ready frag
static __device__ __forceinline__ short8_t bn8(int4 v, const float* a8, const float* c8) {
    ushort* pv = (ushort*)&v;
    #pragma unroll
    for (int e = 0; e < 8; ++e)
        pv[e] = f2bfx(fmaxf(a8[e] * bf2f(pv[e]) + c8[e], 0.f));
    return i4s8(v);
}

// ---- x [32][32][32768] f32  ->  xt [32768][1024] bf16 (row = b*32+i) ----
__global__ __launch_bounds__(256) void transpose_x_kernel(
    const float* __restrict__ x, ushort* __restrict__ xt)
{
    __shared__ ushort T[64][66];
    const int tid = threadIdx.x;
    const int n0 = blockIdx.x * 64, c0 = blockIdx.y * 64;
    const int lane64 = tid & 63, rb = (tid >> 6) * 16;
    #pragma unroll
    for (int r = 0; r < 16; ++r) {
        int c_l = rb + r;
        T[c_l][lane64] = f2bfx(x[(size_t)(c0 + c_l) * NIN + n0 + lane64]);
    }
    __syncthreads();
    #pragma unroll
    for (int r = 0; r < 16; ++r) {
        int n_l = rb + r;
        xt[(size_t)(n0 + n_l) * 1024 + c0 + lane64] = T[lane64][n_l];
    }
}

// ---- weight prep into LDS-segment layouts (+ zero stats stripes) ----
__global__ __launch_bounds__(256) void prep_w_kernel(
    const float* __restrict__ W1, const float* __restrict__ W2,
    const float* __restrict__ We,
    ushort* __restrict__ w1p, ushort* __restrict__ w2p, ushort* __restrict__ wep,
    float* __restrict__ stz)
{
    int t = blockIdx.x * 256 + threadIdx.x;
    const int N1 = 18432, N2 = 36864, N3 = 2048;
    if (t < 3 * ST_STRIPES * 128) stz[t] = 0.f;
    if (t < N1) {
        int e = t & 7, o = (t >> 3) & 63, seg = t >> 9;   // seg = k*4+fcg
        int fcg = seg & 3, k = seg >> 2;
        int i = fcg * 8 + e;
        w1p[t] = f2bfx(W1[o * 288 + i * 9 + k]);
    } else if (t < N1 + N2) {
        int t2 = t - N1;
        int e = t2 & 7, o = (t2 >> 3) & 63, seg = t2 >> 9; // seg = k*8+kk*4+fcg
        int fcg = seg & 3, kk = (seg >> 2) & 1, k = seg >> 3;
        int ci = kk * 32 + fcg * 8 + e;
        w2p[t2] = f2bfx(W2[o * 576 + ci * 9 + k]);
    } else if (t < N1 + N2 + N3) {
        int t3 = t - N1 - N2;
        wep[t3] = f2bfx(We[t3]);
    }
}

// ---- conv1 + ident fused: 8 waves/block, wave owns one n.
//      W1 in LDS; conv A-gather depth-4 pipeline; pool gathers ride the tail;
//      ident MFMA reuses acc.  out1 rows written in CONTIGUOUS-GATHER layout
//      [n][kk=ch>>5][b][ch&31] so conv2's 4 gather instrs are each 1KB-dense. ----
__global__ __launch_bounds__(512, 2) void conv1i_kernel(
    const ushort* __restrict__ xt, const int* __restrict__ idx1,
    const int* __restrict__ pool_idx, const ushort* __restrict__ w1p,
    const ushort* __restrict__ wep,
    ushort* __restrict__ out1, ushort* __restrict__ identt,
    float* __restrict__ st1g, float* __restrict__ st3g)
{
    __shared__ __align__(16) ushort Wl[18432];   // 36864 B
    __shared__ float Ls1[128], Ls3[128];
    const int tid = threadIdx.x;
    const int lane = tid & 63, wv = tid >> 6;
    const int n = __builtin_amdgcn_readfirstlane(blockIdx.x * 8 + wv);
    const int l15 = lane & 15, fcg = lane >> 4, fc = fcg * 8;

    for (int i = tid; i < 2304; i += 512)
        ((int4*)Wl)[i] = ((const int4*)w1p)[i];
    if (tid < 128) { Ls1[tid] = 0.f; Ls3[tid] = 0.f; }

    int rows[9], prow[4];
    {
        const int* idxn = idx1 + n * 9;
        #pragma unroll
        for (int t = 0; t < 9; ++t) rows[t] = idxn[t];
        const int* pn = pool_idx + n * 4;
        #pragma unroll
        for (int t = 0; t < 4; ++t) prow[t] = pn[t];
    }
    __syncthreads();

    f32x4_t acc[2][4];
    #pragma unroll
    for (int m = 0; m < 2; ++m)
        #pragma unroll
        for (int nt = 0; nt < 4; ++nt) acc[m][nt] = (f32x4_t){0.f, 0.f, 0.f, 0.f};

    int4 A0[2], A1[2], A2[2], A3[2];

#define C1_PRE(K, A) { \
    const ushort* rp = xt + (size_t)rows[K] * 1024 + l15 * 32 + fc; \
    A[0] = *(const int4*)rp; \
    A[1] = *(const int4*)(rp + 512); }

#define C1_PPRE(KP, A) { \
    const ushort* rp = xt + (size_t)prow[KP] * 1024 + l15 * 32 + fc; \
    A[0] = *(const int4*)rp; \
    A[1] = *(const int4*)(rp + 512); }

#define C1_BODY(K, A) { \
    const ushort* wp = Wl + ((K) * 4 + fcg) * 512; \
    short8_t b0 = *(const short8_t*)(wp + l15 * 8); \
    short8_t b1 = *(const short8_t*)(wp + (16 + l15) * 8); \
    short8_t b2 = *(const short8_t*)(wp + (32 + l15) * 8); \
    short8_t b3 = *(const short8_t*)(wp + (48 + l15) * 8); \
    short8_t af0 = i4s8(A[0]), af1 = i4s8(A[1]); \
    acc[0][0] = MF(af0, b0, acc[0][0]); acc[1][0] = MF(af1, b0, acc[1][0]); \
    acc[0][1] = MF(af0, b1, acc[0][1]); acc[1][1] = MF(af1, b1, acc[1][1]); \
    acc[0][2] = MF(af0, b2, acc[0][2]); acc[1][2] = MF(af1, b2, acc[1][2]); \
    acc[0][3] = MF(af0, b3, acc[0][3]); acc[1][3] = MF(af1, b3, acc[1][3]); }

    C1_PRE(0, A0); C1_PRE(1, A1); C1_PRE(2, A2); C1_PRE(3, A3);
    C1_BODY(0, A0); C1_PRE(4, A0);
    C1_BODY(1, A1); C1_PRE(5, A1);
    C1_BODY(2, A2); C1_PRE(6, A2);
    C1_BODY(3, A3); C1_PRE(7, A3);
    C1_BODY(4, A0); C1_PRE(8, A0);
    C1_BODY(5, A1); C1_PPRE(0, A1);
    C1_BODY(6, A2); C1_PPRE(1, A2);
    C1_BODY(7, A3); C1_PPRE(2, A3);
    C1_BODY(8, A0);
#undef C1_PRE
#undef C1_BODY

    // conv epilogue: store raw out1 in [kk][b][c32] row layout + stats1
    const size_t outbase = (size_t)n * 2048;
    #pragma unroll
    for (int m = 0; m < 2; ++m)
        #pragma unroll
        for (int nt = 0; nt < 4; ++nt)
            #pragma unroll
            for (int j = 0; j < 4; ++j) {
                int b = m * 16 + (lane >> 4) * 4 + j;
                int o = nt * 16 + l15;
                out1[outbase + (o >> 5) * 1024 + b * 32 + (o & 31)] = f2bfx(acc[m][nt][j]);
            }
    #pragma unroll
    for (int nt = 0; nt < 4; ++nt) {
        float s = 0.f, q = 0.f;
        #pragma unroll
        for (int m = 0; m < 2; ++m)
            #pragma unroll
            for (int j = 0; j < 4; ++j) { float v = acc[m][nt][j]; s += v; q += v * v; }
        s += __shfl_xor(s, 16); s += __shfl_xor(s, 32);
        q += __shfl_xor(q, 16); q += __shfl_xor(q, 32);
        if (lane < 16) {
            atomicAdd(&Ls1[nt * 16 + lane], s);
            atomicAdd(&Ls1[64 + nt * 16 + lane], q);
        }
    }

    // pool: last row + sum (A1..A3 hold pool rows 0..2)
    int4 P3[2];
    C1_PPRE(3, P3);
#undef C1_PPRE
    float s0[8], s1[8];
    #pragma unroll
    for (int e = 0; e < 8; ++e) { s0[e] = 0.f; s1[e] = 0.f; }
    {
        const ushort* p;
        p = (const ushort*)&A1[0];
        #pragma unroll
        for (int e = 0; e < 8; ++e) s0[e] += bf2f(p[e]);
        p = (const ushort*)&A1[1];
        #pragma unroll
        for (int e = 0; e < 8; ++e) s1[e] += bf2f(p[e]);
        p = (const ushort*)&A2[0];
        #pragma unroll
        for (int e = 0; e < 8; ++e) s0[e] += bf2f(p[e]);
        p = (const ushort*)&A2[1];
        #pragma unroll
        for (int e = 0; e < 8; ++e) s1[e] += bf2f(p[e]);
        p = (const ushort*)&A3[0];
        #pragma unroll
        for (int e = 0; e < 8; ++e) s0[e] += bf2f(p[e]);
        p = (const ushort*)&A3[1];
        #pragma unroll
        for (int e = 0; e < 8; ++e) s1[e] += bf2f(p[e]);
        p = (const ushort*)&P3[0];
        #pragma unroll
        for (int e = 0; e < 8; ++e) s0[e] += bf2f(p[e]);
        p = (const ushort*)&P3[1];
        #pragma unroll
        for (int e = 0; e < 8; ++e) s1[e] += bf2f(p[e]);
    }
    short8_t paf0, paf1;
    {
        int4 v0, v1; ushort* p0 = (ushort*)&v0; ushort* p1 = (ushort*)&v1;
        #pragma unroll
        for (int e = 0; e < 8; ++e) {
            p0[e] = f2bfx(s0[e] * 0.25f);
            p1[e] = f2bfx(s1[e] * 0.25f);
        }
        paf0 = i4s8(v0); paf1 = i4s8(v1);
    }
    short8_t bfr[4];
    {
        const ushort* wpf = wep + l15 * 32 + fc;
        #pragma unroll
        for (int nt = 0; nt < 4; ++nt)
            bfr[nt] = *(const short8_t*)(wpf + nt * 512);
    }
    #pragma unroll
    for (int nt = 0; nt < 4; ++nt) {
        acc[0][nt] = (f32x4_t){0.f, 0.f, 0.f, 0.f};
        acc[1][nt] = (f32x4_t){0.f, 0.f, 0.f, 0.f};
        acc[0][nt] = MF(paf0, bfr[nt], acc[0][nt]);
        acc[1][nt] = MF(paf1, bfr[nt], acc[1][nt]);
    }
    #pragma unroll
    for (int m = 0; m < 2; ++m)
        #pragma unroll
        for (int nt = 0; nt < 4; ++nt)
            #pragma unroll
            for (int j = 0; j < 4; ++j) {
                int b = m * 16 + (lane >> 4) * 4 + j;
                int o = nt * 16 + l15;
                identt[outbase + b * 64 + o] = f2bfx(acc[m][nt][j]);   // old layout
            }
    #pragma unroll
    for (int nt = 0; nt < 4; ++nt) {
        float s = 0.f, q = 0.f;
        #pragma unroll
        for (int m = 0; m < 2; ++m)
            #pragma unroll
            for (int j = 0; j < 4; ++j) { float v = acc[m][nt][j]; s += v; q += v * v; }
        s += __shfl_xor(s, 16); s += __shfl_xor(s, 32);
        q += __shfl_xor(q, 16); q += __shfl_xor(q, 32);
        if (lane < 16) {
            atomicAdd(&Ls3[nt * 16 + lane], s);
            atomicAdd(&Ls3[64 + nt * 16 + lane], q);
        }
    }
    __syncthreads();
    if (tid < 128) {
        atomicAdd(&st1g[(blockIdx.x & (ST_STRIPES - 1)) * 128 + tid], Ls1[tid]);
        atomicAdd(&st3g[(blockIdx.x & (ST_STRIPES - 1)) * 128 + tid], Ls3[tid]);
    }
}

// ---- conv2: 8 waves/block, wave owns one n. W2 in LDS; A gathered
//      direct-to-fragment from out1 in [kk][b][c32] layout — each of the 4
//      gather instrs reads a CONTIGUOUS 1KB (8 cache lines, fully used).
//      BN1+ReLU fused in regs; depth-3 pipeline, (512,2) headroom ----
__global__ __launch_bounds__(512, 2) void conv2_kernel(
    const ushort* __restrict__ out1raw, const int* __restrict__ idx2,
    const ushort* __restrict__ w2p, const float* __restrict__ ac1,
    ushort* __restrict__ out2, float* __restrict__ st)
{
    __shared__ __align__(16) ushort Wl[36864];   // 73728 B
    __shared__ float Ls[128];
    const int tid = threadIdx.x;
    const int lane = tid & 63, wv = tid >> 6;
    const int n = __builtin_amdgcn_readfirstlane(blockIdx.x * 8 + wv);
    const int l15 = lane & 15, fcg = lane >> 4, fc = fcg * 8;

    for (int i = tid; i < 4608; i += 512)
        ((int4*)Wl)[i] = ((const int4*)w2p)[i];
    if (tid < 128) Ls[tid] = 0.f;

    int rows[9];
    {
        const int* idxn = idx2 + n * 9;
        #pragma unroll
        for (int t = 0; t < 9; ++t) rows[t] = idxn[t];
    }
    float a0r[8], c0r[8], a1r[8], c1r[8];
    #pragma unroll
    for (int e = 0; e < 8; ++e) {
        a0r[e] = ac1[fc + e];       c0r[e] = ac1[64 + fc + e];
        a1r[e] = ac1[32 + fc + e];  c1r[e] = ac1[96 + fc + e];
    }
    __syncthreads();

    f32x4_t acc[2][4];
    #pragma unroll
    for (int m = 0; m < 2; ++m)
        #pragma unroll
        for (int nt = 0; nt < 4; ++nt) acc[m][nt] = (f32x4_t){0.f, 0.f, 0.f, 0.f};

    int4 A0[4], A1[4], A2[4];

// out1 row layout: [kk:2][b:32][c:32].  A[i]:
//   A[0] m0 kk0: b=l15,     off = l15*32+fc           (bytes l15*64+fcg*16: 1KB dense)
//   A[2] m1 kk0: b=16+l15,  off = 512+l15*32+fc
//   A[1] m0 kk1:            off = 1024+l15*32+fc
//   A[3] m1 kk1:            off = 1536+l15*32+fc
#define C2_PRE(K, A) { \
    const ushort* rp = out1raw + (size_t)rows[K] * 2048 + l15 * 32 + fc; \
    A[0] = *(const int4*)rp; \
    A[2] = *(const int4*)(rp + 512); \
    A[1] = *(const int4*)(rp + 1024); \
    A[3] = *(const int4*)(rp + 1536); }

#define C2_BODY(K, A) { \
    const ushort* wp0 = Wl + ((K) * 8 + fcg) * 512; \
    const ushort* wp1 = wp0 + 2048; \
    short8_t b00 = *(const short8_t*)(wp0 + l15 * 8); \
    short8_t b10 = *(const short8_t*)(wp0 + (16 + l15) * 8); \
    short8_t b20 = *(const short8_t*)(wp0 + (32 + l15) * 8); \
    short8_t b30 = *(const short8_t*)(wp0 + (48 + l15) * 8); \
    short8_t b01 = *(const short8_t*)(wp1 + l15 * 8); \
    short8_t b11 = *(const short8_t*)(wp1 + (16 + l15) * 8); \
    short8_t b21 = *(const short8_t*)(wp1 + (32 + l15) * 8); \
    short8_t b31 = *(const short8_t*)(wp1 + (48 + l15) * 8); \
    short8_t af00 = bn8(A[0], a0r, c0r); \
    short8_t af01 = bn8(A[1], a1r, c1r); \
    short8_t af10 = bn8(A[2], a0r, c0r); \
    short8_t af11 = bn8(A[3], a1r, c1r); \
    acc[0][0] = MF(af00, b00, acc[0][0]); acc[0][0] = MF(af01, b01, acc[0][0]); \
    acc[0][1] = MF(af00, b10, acc[0][1]); acc[0][1] = MF(af01, b11, acc[0][1]); \
    acc[0][2] = MF(af00, b20, acc[0][2]); acc[0][2] = MF(af01, b21, acc[0][2]); \
    acc[0][3] = MF(af00, b30, acc[0][3]); acc[0][3] = MF(af01, b31, acc[0][3]); \
    acc[1][0] = MF(af10, b00, acc[1][0]); acc[1][0] = MF(af11, b01, acc[1][0]); \
    acc[1][1] = MF(af10, b10, acc[1][1]); acc[1][1] = MF(af11, b11, acc[1][1]); \
    acc[1][2] = MF(af10, b20, acc[1][2]); acc[1][2] = MF(af11, b21, acc[1][2]); \
    acc[1][3] = MF(af10, b30, acc[1][3]); acc[1][3] = MF(af11, b31, acc[1][3]); }

    C2_PRE(0, A0); C2_PRE(1, A1); C2_PRE(2, A2);
    C2_BODY(0, A0); C2_PRE(3, A0);
    C2_BODY(1, A1); C2_PRE(4, A1);
    C2_BODY(2, A2); C2_PRE(5, A2);
    C2_BODY(3, A0); C2_PRE(6, A0);
    C2_BODY(4, A1); C2_PRE(7, A1);
    C2_BODY(5, A2); C2_PRE(8, A2);
    C2_BODY(6, A0);
    C2_BODY(7, A1);
    C2_BODY(8, A2);
#undef C2_PRE
#undef C2_BODY

    const size_t outbase = (size_t)n * 2048;
    #pragma unroll
    for (int m = 0; m < 2; ++m)
        #pragma unroll
        for (int nt = 0; nt < 4; ++nt)
            #pragma unroll
            for (int j = 0; j < 4; ++j) {
                int b = m * 16 + (lane >> 4) * 4 + j;
                int o = nt * 16 + l15;
                out2[outbase + b * 64 + o] = f2bfx(acc[m][nt][j]);   // old layout
            }
    #pragma unroll
    for (int nt = 0; nt < 4; ++nt) {
        float s = 0.f, q = 0.f;
        #pragma unroll
        for (int m = 0; m < 2; ++m)
            #pragma unroll
            for (int j = 0; j < 4; ++j) { float v = acc[m][nt][j]; s += v; q += v * v; }
        s += __shfl_xor(s, 16); s += __shfl_xor(s, 32);
        q += __shfl_xor(q, 16); q += __shfl_xor(q, 32);
        if (lane < 16) {
            atomicAdd(&Ls[nt * 16 + lane], s);
            atomicAdd(&Ls[64 + nt * 16 + lane], q);
        }
    }
    __syncthreads();
    if (tid < 128) atomicAdd(&st[(blockIdx.x & (ST_STRIPES - 1)) * 128 + tid], Ls[tid]);
}

// ---- finalize BN affine from striped partials ----
__global__ void finalize_kernel(const float* __restrict__ st, const float* __restrict__ g,
                                const float* __restrict__ bet, float* __restrict__ ac)
{
    int o = threadIdx.x;
    if (o >= 64) return;
    float s = 0.f, q = 0.f;
    for (int i = 0; i < ST_STRIPES; ++i) { s += st[i * 128 + o]; q += st[i * 128 + 64 + o]; }
    float mean = s * (1.0f / MTOT);
    float var  = q * (1.0f / MTOT) - mean * mean;
    float a = g[o] * rsqrtf(var + 1e-5f);
    ac[o] = a;
    ac[64 + o] = bet[o] - a * mean;
}

__global__ void finalize_dual_kernel(
    const float* __restrict__ stA, const float* __restrict__ gA, const float* __restrict__ bA,
    const float* __restrict__ stB, const float* __restrict__ gB, const float* __restrict__ bB,
    float* __restrict__ acA, float* __restrict__ acB)
{
    int o = threadIdx.x;
    if (o >= 64) return;
    const float* st = blockIdx.x ? stB : stA;
    const float* g  = blockIdx.x ? gB  : gA;
    const float* bt = blockIdx.x ? bB  : bA;
    float* ac       = blockIdx.x ? acB : acA;
    float s = 0.f, q = 0.f;
    for (int i = 0; i < ST_STRIPES; ++i) { s += st[i * 128 + o]; q += st[i * 128 + 64 + o]; }
    float mean = s * (1.0f / MTOT);
    float var  = q * (1.0f / MTOT) - mean * mean;
    float a = g[o] * rsqrtf(var + 1e-5f);
    ac[o] = a;
    ac[64 + o] = bt[o] - a * mean;
}

// ---- final: d_out[bo][n] = relu(a2*out2 + c2 + a3*identt + c3), with transpose ----
__global__ __launch_bounds__(256) void final_combine_kernel(
    const ushort* __restrict__ out2, const ushort* __restrict__ idt,
    const float* __restrict__ ac2, const float* __restrict__ ac3,
    float* __restrict__ dout)
{
    __shared__ float tile[64][65];
    const int tid = threadIdx.x;
    const int n0 = blockIdx.x * 64, bo0 = blockIdx.y * 64;
    const int lane64 = tid & 63, rb = (tid >> 6) * 16;
    const int o = lane64;  // bo0 is a multiple of 64
    const float a2 = ac2[o], c2 = ac2[64 + o], a3 = ac3[o], c3 = ac3[64 + o];
    #pragma unroll
    for (int r = 0; r < 16; ++r) {
        int n_l = rb + r;
        size_t p = (size_t)(n0 + n_l) * 2048 + bo0 + lane64;
        float v = a2 * bf2f(out2[p]) + c2 + a3 * bf2f(idt[p]) + c3;
        tile[n_l][lane64] = fmaxf(v, 0.f);
    }
    __syncthreads();
    #pragma unroll
    for (int r = 0; r < 16; ++r) {
        int bo_l = rb + r;
        dout[(size_t)(bo0 + bo_l) * NOUT + n0 + lane64] = tile[lane64][bo_l];
    }
}

extern "C" void kernel_launch(void* const* d_in, const int* in_sizes, int n_in,
                              void* d_out, int out_size, void* d_ws, size_t ws_size,
                              hipStream_t stream)
{
    const float* x     = (const float*)d_in[0];
    const float* W1    = (const float*)d_in[1];
    const float* W2    = (const float*)d_in[3];
    const float* We    = (const float*)d_in[5];
    const float* g1    = (const float*)d_in[7];
    const float* beta1 = (const float*)d_in[8];
    const float* g2    = (const float*)d_in[9];
    const float* beta2 = (const float*)d_in[10];
    const float* g3    = (const float*)d_in[11];
    const float* beta3 = (const float*)d_in[12];
    const int* idx1    = (const int*)d_in[13];
    const int* idx2    = (const int*)d_in[14];
    const int* pool_idx= (const int*)d_in[15];
    float* dout = (float*)d_out;

    char* ws = (char*)d_ws;
    const size_t off_xt   = 0;                    // 67108864
    const size_t off_out1 = 67108864;             // 33554432
    const size_t off_out2 = 100663296;             // 33554432
    const size_t off_id   = 134217728;             // 33554432
    const size_t off_w1p  = 167772160;             // 36864
    const size_t off_w2p  = 167809024;             // 73728
    const size_t off_wep  = 167882752;             // 4096
    const size_t off_st   = 167886848;             // 3 * 64*128*4 = 98304
    const size_t off_ac   = 167985152;             // 1536
    const size_t need     = 167986688;
    if (ws_size < need) return;  // insufficient workspace — fail visibly

    ushort* xt   = (ushort*)(ws + off_xt);
    ushort* out1 = (ushort*)(ws + off_out1);
    ushort* out2 = (ushort*)(ws + off_out2);
    ushort* idt  = (ushort*)(ws + off_id);
    ushort* w1p  = (ushort*)(ws + off_w1p);
    ushort* w2p  = (ushort*)(ws + off_w2p);
    ushort* wep  = (ushort*)(ws + off_wep);
    float*  st1  = (float*)(ws + off_st);
    float*  st2  = st1 + 64 * 128;
    float*  st3  = st1 + 2 * 64 * 128;
    float*  ac1  = (float*)(ws + off_ac);
    float*  ac2  = ac1 + 128;
    float*  ac3  = ac1 + 256;

    prep_w_kernel<<<224, 256, 0, stream>>>(W1, W2, We, w1p, w2p, wep, st1);
    transpose_x_kernel<<<dim3(512, 16), 256, 0, stream>>>(x, xt);
    conv1i_kernel<<<1024, 512, 0, stream>>>(xt, idx1, pool_idx, w1p, wep, out1, idt, st1, st3);
    finalize_dual_kernel<<<2, 64, 0, stream>>>(st1, g1, beta1, st3, g3, beta3, ac1, ac3);
    conv2_kernel<<<1024, 512, 0, stream>>>(out1, idx2, w2p, ac1, out2, st2);
    finalize_kernel<<<1, 64, 0, stream>>>(st2, g2, beta2, ac2);
    final_combine_kernel<<<dim3(128, 32), 256, 0, stream>>>(out2, idt, ac2, ac3, dout);
}